// Round 6
// baseline (190.056 us; speedup 1.0000x reference)
//
#include <hip/hip_runtime.h>
#include <hip/hip_bf16.h>
#include <math.h>

#define NB 32
#define NS 512
#define ND 512
#define NH 8
#define NDK 64

typedef __attribute__((ext_vector_type(8))) short bfrag;   // 8 x bf16 (4 VGPRs)
typedef __attribute__((ext_vector_type(4))) float f32x4;   // MFMA C/D

// 0.125 * log2(e): folds 1/sqrt(dk) into the exp2 argument
#define SCL 0.18033688011112042592f

__device__ __forceinline__ ushort f2bf(float f) {
    union { float f; unsigned u; } v; v.f = f;
    unsigned u = v.u;
    return (ushort)((u + 0x7fffu + ((u >> 16) & 1u)) >> 16);   // RNE
}

__device__ __forceinline__ unsigned pk2bf(float a, float b) {
    __hip_bfloat162 h = __float22bfloat162_rn(make_float2(a, b));
    return *reinterpret_cast<unsigned*>(&h);
}

// async global->LDS DMA, 16B/lane; LDS dest = wave-uniform base + lane*16
__device__ __forceinline__ void async16(const ushort* g, ushort* l) {
    __builtin_amdgcn_global_load_lds(
        (const __attribute__((address_space(1))) unsigned int*)g,
        (__attribute__((address_space(3))) unsigned int*)l, 16, 0, 0);
}

// ---------------------------------------------------------------------------
// prep: blocks [0,8192) = x fp32->bf16 ; blocks [8192,8448) = weight
// transpose+convert. WT[(which*8+h)*64+n][d], WoT[n][d].
// ---------------------------------------------------------------------------
__global__ __launch_bounds__(256) void prep(const float* __restrict__ x,
                                            const float* __restrict__ Wq,
                                            const float* __restrict__ Wk,
                                            const float* __restrict__ Wv,
                                            const float* __restrict__ Wo,
                                            ushort* __restrict__ xb,
                                            ushort* __restrict__ WT,
                                            ushort* __restrict__ WoT) {
    __shared__ ushort T[64 * 72];
    const int tid = threadIdx.x;
    if (blockIdx.x < 8192) {
        const int idx = blockIdx.x * 256 + tid;
        const float4 v = reinterpret_cast<const float4*>(x)[idx];
        ushort4 o;
        o.x = f2bf(v.x); o.y = f2bf(v.y); o.z = f2bf(v.z); o.w = f2bf(v.w);
        reinterpret_cast<ushort4*>(xb)[idx] = o;
        return;
    }
    const int bid = blockIdx.x - 8192;
    const float* src; ushort* dst; int d0, n0, stride;
    if (bid < 192) {
        const int which = bid >> 6, h = (bid >> 3) & 7, rt = bid & 7;
        const float* Ws = (which == 0) ? Wq : (which == 1) ? Wk : Wv;
        src = Ws + (size_t)h * ND * NDK;
        dst = WT + (size_t)(which * NH + h) * NDK * ND;
        d0 = rt * 64; n0 = 0; stride = NDK;
    } else {
        const int t = bid - 192, rt = t >> 3, ct = t & 7;
        src = Wo; dst = WoT;
        d0 = rt * 64; n0 = ct * 64; stride = ND;
    }
    #pragma unroll
    for (int i = 0; i < 4; i++) {
        const int u = i * 256 + tid;
        const int row = u >> 4, cq = u & 15;
        const float4 v = *reinterpret_cast<const float4*>(&src[(size_t)(d0 + row) * stride + n0 + cq * 4]);
        T[(cq * 4 + 0) * 72 + row] = f2bf(v.x);
        T[(cq * 4 + 1) * 72 + row] = f2bf(v.y);
        T[(cq * 4 + 2) * 72 + row] = f2bf(v.z);
        T[(cq * 4 + 3) * 72 + row] = f2bf(v.w);
    }
    __syncthreads();
    #pragma unroll
    for (int i = 0; i < 2; i++) {
        const int u = i * 256 + tid;
        const int n = u >> 3, dq = u & 7;
        *reinterpret_cast<float4*>(&dst[(size_t)(n0 + n) * ND + d0 + dq * 8]) =
            *reinterpret_cast<float4*>(&T[n * 72 + dq * 8]);
    }
}

// ---------------------------------------------------------------------------
// proj: blocks [0,1024) = Q|K GEMM (128x128 tiles on [16384x1024]);
//       blocks [1024,1536) = V^T GEMM (per (b,h): VT[dk][s], 64x256 tiles).
// Union LDS (40 KB). B-slots permuted -> packed 8B bf16 stores.
// ---------------------------------------------------------------------------
__global__ __launch_bounds__(256) void proj(const ushort* __restrict__ xb,
                                            const ushort* __restrict__ WT,
                                            const float* __restrict__ bias,
                                            ushort* __restrict__ QKb,
                                            ushort* __restrict__ VT) {
    __shared__ ushort sm[20480];   // 40 KB
    const int tid = threadIdx.x;
    const int w = tid >> 6, lane = tid & 63, quad = lane >> 4, l16 = lane & 15;
    const int lr = lane >> 3, lc = lane & 7, cs = lc ^ lr, swz = l16 & 7;
    const float bb = bias[0];

    f32x4 acc[4][4];
    #pragma unroll
    for (int i = 0; i < 4; i++)
        #pragma unroll
        for (int j = 0; j < 4; j++) acc[i][j] = (f32x4){0.f, 0.f, 0.f, 0.f};

    if (blockIdx.x < 1024) {
        ushort* As = sm;            // 128x64
        ushort* Bs = sm + 8192;     // 128x64
        const int bid = blockIdx.x;
        const int m0 = (bid & 127) * 128, n0 = (bid >> 7) * 128;
        const int rw = (w & 1) * 64, cw = (w >> 1) * 64;
        for (int d0 = 0; d0 < ND; d0 += 64) {
            __syncthreads();
            #pragma unroll
            for (int t = 0; t < 4; t++) {
                const int rb = (w * 4 + t) * 8;
                async16(&xb[(size_t)(m0 + rb + lr) * ND + d0 + cs * 8], &As[rb * 64]);
                const int slot = rb + lr, nn = slot & 63;
                const int j = n0 + (slot & 64) + 4 * (nn & 15) + (nn >> 4);
                async16(&WT[(size_t)j * ND + d0 + cs * 8], &Bs[rb * 64]);
            }
            __syncthreads();
            #pragma unroll
            for (int ks = 0; ks < 2; ks++) {
                const int ch = ((ks * 4 + quad) ^ swz) * 8;
                bfrag a[4], bo[4];
                #pragma unroll
                for (int rf = 0; rf < 4; rf++) a[rf] = *(const bfrag*)&As[(rw + rf * 16 + l16) * 64 + ch];
                #pragma unroll
                for (int cf = 0; cf < 4; cf++) bo[cf] = *(const bfrag*)&Bs[(cw + cf * 16 + l16) * 64 + ch];
                #pragma unroll
                for (int rf = 0; rf < 4; rf++)
                    #pragma unroll
                    for (int cf = 0; cf < 4; cf++)
                        acc[rf][cf] = __builtin_amdgcn_mfma_f32_16x16x32_bf16(a[rf], bo[cf], acc[rf][cf], 0, 0, 0);
            }
        }
        #pragma unroll
        for (int rf = 0; rf < 4; rf++)
            #pragma unroll
            for (int r = 0; r < 4; r++) {
                const int row = m0 + rw + rf * 16 + quad * 4 + r;
                uint2 u;
                u.x = pk2bf(acc[rf][0][r] + bb, acc[rf][1][r] + bb);
                u.y = pk2bf(acc[rf][2][r] + bb, acc[rf][3][r] + bb);
                *(uint2*)&QKb[(size_t)row * 1024 + n0 + cw + 4 * l16] = u;
            }
    } else {
        ushort* As = sm;            // 64x64
        ushort* Bs = sm + 4096;     // 256x64
        const int bid = blockIdx.x - 1024;
        const int bh = bid >> 1, s0 = (bid & 1) * 256;
        const int b = bh >> 3, h = bh & 7;
        const int cw = w * 64;
        const ushort* Av = WT + (size_t)(2 * NH + h) * NDK * ND;
        const ushort* xrow = xb + (size_t)b * NS * ND;
        for (int d0 = 0; d0 < ND; d0 += 64) {
            __syncthreads();
            #pragma unroll
            for (int t = 0; t < 2; t++) {
                const int rb = w * 16 + t * 8;
                async16(&Av[(size_t)(rb + lr) * ND + d0 + cs * 8], &As[rb * 64]);
            }
            #pragma unroll
            for (int t = 0; t < 8; t++) {
                const int rb = (w * 8 + t) * 8;
                const int slot = rb + lr, nn = slot & 63;
                const int js = s0 + (slot & 192) + 4 * (nn & 15) + (nn >> 4);
                async16(&xrow[(size_t)js * ND + d0 + cs * 8], &Bs[rb * 64]);
            }
            __syncthreads();
            #pragma unroll
            for (int ks = 0; ks < 2; ks++) {
                const int ch = ((ks * 4 + quad) ^ swz) * 8;
                bfrag a[4], bo[4];
                #pragma unroll
                for (int rf = 0; rf < 4; rf++) a[rf] = *(const bfrag*)&As[(rf * 16 + l16) * 64 + ch];
                #pragma unroll
                for (int cf = 0; cf < 4; cf++) bo[cf] = *(const bfrag*)&Bs[(cw + cf * 16 + l16) * 64 + ch];
                #pragma unroll
                for (int rf = 0; rf < 4; rf++)
                    #pragma unroll
                    for (int cf = 0; cf < 4; cf++)
                        acc[rf][cf] = __builtin_amdgcn_mfma_f32_16x16x32_bf16(a[rf], bo[cf], acc[rf][cf], 0, 0, 0);
            }
        }
        ushort* vbase = VT + (size_t)bh * NDK * NS;
        #pragma unroll
        for (int rf = 0; rf < 4; rf++)
            #pragma unroll
            for (int r = 0; r < 4; r++) {
                const int dk = rf * 16 + quad * 4 + r;
                uint2 u;
                u.x = pk2bf(acc[rf][0][r] + bb, acc[rf][1][r] + bb);
                u.y = pk2bf(acc[rf][2][r] + bb, acc[rf][3][r] + bb);
                *(uint2*)&vbase[(size_t)dk * NS + s0 + cw + 4 * l16] = u;
            }
    }
}

// ---------------------------------------------------------------------------
// Flash attention, 128-row Q tile. 1024 blocks x 256 — fully co-resident
// (4 blocks/CU @ 34.4 KB LDS). Q fragments held in registers; Ps overlays
// the Qs staging buffer (transition guarded by s_waitcnt lgkmcnt(0) +
// barrier). Fixed-max softmax w/ fma-folded mask; row sums via ones-MFMA.
// ---------------------------------------------------------------------------
__global__ __launch_bounds__(256) void attn_mfma(const ushort* __restrict__ QKb,
                                                 const ushort* __restrict__ VT,
                                                 const int* __restrict__ mask,
                                                 ushort* __restrict__ Hb) {
    __shared__ ushort QP[128 * 72];   // Q staged at stride 64; reused as Ps stride 72
    __shared__ ushort Ks[64 * 64];
    __shared__ ushort Vs[64 * 64];
    const int id = blockIdx.x;
    const int bh = id & 255, b = bh >> 3, h = bh & 7;
    const int s0 = (id >> 8) * 128;
    const int tid = threadIdx.x;
    const int w = tid >> 6, lane = tid & 63, quad = lane >> 4, l16 = lane & 15;
    const int lr = lane >> 3, lc = lane & 7, cs = lc ^ lr, swz = l16 & 7;

    const ushort* qbase = QKb + (size_t)(b * NS + s0) * 1024 + h * 64;
    const ushort* kbase = QKb + (size_t)(b * NS) * 1024 + 512 + h * 64;
    const ushort* vbase = VT + (size_t)(b * NH + h) * NDK * NS;

    #pragma unroll
    for (int t = 0; t < 4; t++) {
        const int rb = (w * 4 + t) * 8;
        async16(&qbase[(size_t)(rb + lr) * 1024 + cs * 8], &QP[rb * 64]);
    }
    __syncthreads();   // drains Q DMA (vmcnt0 before barrier)

    // Q fragments -> registers (wave rows w*32 .. w*32+31)
    bfrag qf[2][2];
    #pragma unroll
    for (int ks = 0; ks < 2; ks++)
        #pragma unroll
        for (int rf = 0; rf < 2; rf++)
            qf[ks][rf] = *(const bfrag*)&QP[(w * 32 + rf * 16 + l16) * 64 + ((ks * 4 + quad) ^ swz) * 8];
    // ensure ALL waves' Q reads have completed before anyone writes Ps here
    asm volatile("s_waitcnt lgkmcnt(0)" ::: "memory");
    __syncthreads();
    ushort* Ps = QP;   // stride 72 from here on

    bfrag ones;
    #pragma unroll
    for (int i = 0; i < 8; i++) ones[i] = (short)0x3F80;   // bf16 1.0

    f32x4 acc_l[2];
    f32x4 acc_o[2][4];
    #pragma unroll
    for (int rf = 0; rf < 2; rf++) {
        acc_l[rf] = (f32x4){0.f, 0.f, 0.f, 0.f};
        #pragma unroll
        for (int c = 0; c < 4; c++) acc_o[rf][c] = (f32x4){0.f, 0.f, 0.f, 0.f};
    }

    for (int kt = 0; kt < 8; kt++) {
        __syncthreads();   // prior iter Ks/Vs frag reads complete
        #pragma unroll
        for (int t = 0; t < 2; t++) {
            const int rb = (w * 2 + t) * 8;
            const int n = rb + lr;
            const int jk = 4 * (n & 15) + (n >> 4);    // source key/dk for slot n
            async16(&kbase[(size_t)(kt * 64 + jk) * 1024 + cs * 8], &Ks[rb * 64]);
            async16(&vbase[(size_t)jk * NS + kt * 64 + cs * 8], &Vs[rb * 64]);
        }
        __syncthreads();   // vmcnt drain: staging visible

        // scores: rows w*32+rf*16+quad*4+r, cols = key 4*l16+c
        f32x4 sc[2][4];
        #pragma unroll
        for (int rf = 0; rf < 2; rf++)
            #pragma unroll
            for (int c = 0; c < 4; c++) sc[rf][c] = (f32x4){0.f, 0.f, 0.f, 0.f};
        #pragma unroll
        for (int ks = 0; ks < 2; ks++) {
            const int ch = ((ks * 4 + quad) ^ swz) * 8;
            bfrag bo[4];
            #pragma unroll
            for (int c = 0; c < 4; c++) bo[c] = *(const bfrag*)&Ks[(c * 16 + l16) * 64 + ch];
            #pragma unroll
            for (int rf = 0; rf < 2; rf++)
                #pragma unroll
                for (int c = 0; c < 4; c++)
                    sc[rf][c] = __builtin_amdgcn_mfma_f32_16x16x32_bf16(qf[ks][rf], bo[c], sc[rf][c], 0, 0, 0);
        }

        // mask folded into fma bias: masked -> -inf -> exp2 = 0
        const int4 mk4 = *(const int4*)&mask[b * NS + kt * 64 + 4 * l16];
        float mb[4];
        mb[0] = mk4.x ? 0.f : -INFINITY;
        mb[1] = mk4.y ? 0.f : -INFINITY;
        mb[2] = mk4.z ? 0.f : -INFINITY;
        mb[3] = mk4.w ? 0.f : -INFINITY;
        #pragma unroll
        for (int rf = 0; rf < 2; rf++) {
            #pragma unroll
            for (int c = 0; c < 4; c++)
                #pragma unroll
                for (int r = 0; r < 4; r++)
                    sc[rf][c][r] = exp2f(fmaf(sc[rf][c][r], SCL, mb[c]));
            #pragma unroll
            for (int r = 0; r < 4; r++) {
                uint2 u;
                u.x = pk2bf(sc[rf][0][r], sc[rf][1][r]);
                u.y = pk2bf(sc[rf][2][r], sc[rf][3][r]);
                *(uint2*)&Ps[(w * 32 + rf * 16 + quad * 4 + r) * 72 + l16 * 4] = u;
            }
        }

        // O += P.V ; rowsum += P.1   (Ps rows wave-private)
        #pragma unroll
        for (int ks = 0; ks < 2; ks++) {
            const int ch = ((ks * 4 + quad) ^ swz) * 8;
            bfrag bo[4];
            #pragma unroll
            for (int c = 0; c < 4; c++) bo[c] = *(const bfrag*)&Vs[(c * 16 + l16) * 64 + ch];
            #pragma unroll
            for (int rf = 0; rf < 2; rf++) {
                const bfrag a = *(const bfrag*)&Ps[(w * 32 + rf * 16 + l16) * 72 + ks * 32 + quad * 8];
                acc_l[rf] = __builtin_amdgcn_mfma_f32_16x16x32_bf16(a, ones, acc_l[rf], 0, 0, 0);
                #pragma unroll
                for (int c = 0; c < 4; c++)
                    acc_o[rf][c] = __builtin_amdgcn_mfma_f32_16x16x32_bf16(a, bo[c], acc_o[rf][c], 0, 0, 0);
            }
        }
    }

    // Hb[b, s, h*64+dk]; acc_o[rf][c][r] = O[row][dk=4*l16+c]
    ushort* hbase = Hb + (size_t)(b * NS + s0) * ND + h * 64;
    #pragma unroll
    for (int rf = 0; rf < 2; rf++)
        #pragma unroll
        for (int r = 0; r < 4; r++) {
            const float inv = 1.0f / acc_l[rf][r];
            const int row = w * 32 + rf * 16 + quad * 4 + r;
            uint2 u;
            u.x = pk2bf(acc_o[rf][0][r] * inv, acc_o[rf][1][r] * inv);
            u.y = pk2bf(acc_o[rf][2][r] * inv, acc_o[rf][3][r] * inv);
            *(uint2*)&hbase[(size_t)row * ND + 4 * l16] = u;
        }
}

// ---------------------------------------------------------------------------
// Output projection GEMM: out[16384][512] = Hb @ WoT^T + bias.
// 128x128 tiles, 512 blocks x 256. Permuted cols -> float4 stores.
// ---------------------------------------------------------------------------
__global__ __launch_bounds__(256) void out_gemm(const ushort* __restrict__ Hb,
                                                const ushort* __restrict__ WoT,
                                                const float* __restrict__ bias,
                                                float* __restrict__ out) {
    __shared__ ushort As[128 * 64];
    __shared__ ushort Bs[128 * 64];
    const int bid = blockIdx.x;
    const int m0 = (bid & 127) * 128, n0 = (bid >> 7) * 128;
    const int tid = threadIdx.x;
    const int w = tid >> 6, lane = tid & 63, quad = lane >> 4, l16 = lane & 15;
    const int lr = lane >> 3, lc = lane & 7, cs = lc ^ lr, swz = l16 & 7;
    const int rw = (w & 1) * 64, cw = (w >> 1) * 64;

    f32x4 acc[4][4];
    #pragma unroll
    for (int i = 0; i < 4; i++)
        #pragma unroll
        for (int j = 0; j < 4; j++) acc[i][j] = (f32x4){0.f, 0.f, 0.f, 0.f};

    for (int d0 = 0; d0 < ND; d0 += 64) {
        __syncthreads();
        #pragma unroll
        for (int t = 0; t < 4; t++) {
            const int rb = (w * 4 + t) * 8;
            async16(&Hb[(size_t)(m0 + rb + lr) * ND + d0 + cs * 8], &As[rb * 64]);
            const int slot = rb + lr, nn = slot & 63;
            const int j = n0 + (slot & 64) + 4 * (nn & 15) + (nn >> 4);
            async16(&WoT[(size_t)j * ND + d0 + cs * 8], &Bs[rb * 64]);
        }
        __syncthreads();
        #pragma unroll
        for (int ks = 0; ks < 2; ks++) {
            const int ch = ((ks * 4 + quad) ^ swz) * 8;
            bfrag a[4], bo[4];
            #pragma unroll
            for (int rf = 0; rf < 4; rf++) a[rf] = *(const bfrag*)&As[(rw + rf * 16 + l16) * 64 + ch];
            #pragma unroll
            for (int cf = 0; cf < 4; cf++) bo[cf] = *(const bfrag*)&Bs[(cw + cf * 16 + l16) * 64 + ch];
            #pragma unroll
            for (int rf = 0; rf < 4; rf++)
                #pragma unroll
                for (int cf = 0; cf < 4; cf++)
                    acc[rf][cf] = __builtin_amdgcn_mfma_f32_16x16x32_bf16(a[rf], bo[cf], acc[rf][cf], 0, 0, 0);
        }
    }

    const float bb = bias[0];
    #pragma unroll
    for (int rf = 0; rf < 4; rf++)
        #pragma unroll
        for (int r = 0; r < 4; r++) {
            const int row = m0 + rw + rf * 16 + quad * 4 + r;
            float4 v;
            v.x = acc[rf][0][r] + bb; v.y = acc[rf][1][r] + bb;
            v.z = acc[rf][2][r] + bb; v.w = acc[rf][3][r] + bb;
            *(float4*)&out[(size_t)row * ND + n0 + cw + 4 * l16] = v;
        }
}

// ---------------------------------------------------------------------------
extern "C" void kernel_launch(void* const* d_in, const int* in_sizes, int n_in,
                              void* d_out, int out_size, void* d_ws, size_t ws_size,
                              hipStream_t stream) {
    const float* x    = (const float*)d_in[0];
    const int*   mask = (const int*)  d_in[1];
    const float* Wq   = (const float*)d_in[2];
    const float* Wk   = (const float*)d_in[3];
    const float* Wv   = (const float*)d_in[4];
    const float* Wo   = (const float*)d_in[5];
    const float* bias = (const float*)d_in[6];
    float* out = (float*)d_out;

    const size_t TE = (size_t)NB * NS * ND;   // 8,388,608
    ushort* xb  = (ushort*)d_ws;
    ushort* WT  = xb  + TE;                              // 1536*512
    ushort* WoT = WT  + (size_t)3 * NH * NDK * ND;       // 512*512
    ushort* QKb = WoT + (size_t)ND * ND;                 // 16384*1024
    ushort* VT  = QKb + (size_t)NB * NS * 2 * ND;        // 32*8*64*512
    ushort* Hb  = VT  + TE;                              // 16384*512

    prep<<<dim3(8448), dim3(256), 0, stream>>>(x, Wq, Wk, Wv, Wo, xb, WT, WoT);
    proj<<<dim3(1536), dim3(256), 0, stream>>>(xb, WT, bias, QKb, VT);
    attn_mfma<<<dim3(1024), dim3(256), 0, stream>>>(QKb, VT, mask, Hb);
    out_gemm<<<dim3(512), dim3(256), 0, stream>>>(Hb, WoT, bias, out);
}

// Round 7
// 179.924 us; speedup vs baseline: 1.0563x; 1.0563x over previous
//
#include <hip/hip_runtime.h>
#include <hip/hip_bf16.h>
#include <math.h>

#define NB 32
#define NS 512
#define ND 512
#define NH 8
#define NDK 64

typedef __attribute__((ext_vector_type(8))) short bfrag;   // 8 x bf16 (4 VGPRs)
typedef __attribute__((ext_vector_type(4))) float f32x4;   // MFMA C/D

// 0.125 * log2(e): folds 1/sqrt(dk) into the exp2 argument
#define SCL 0.18033688011112042592f

__device__ __forceinline__ ushort f2bf(float f) {
    union { float f; unsigned u; } v; v.f = f;
    unsigned u = v.u;
    return (ushort)((u + 0x7fffu + ((u >> 16) & 1u)) >> 16);   // RNE
}

__device__ __forceinline__ unsigned pk2bf(float a, float b) {
    __hip_bfloat162 h = __float22bfloat162_rn(make_float2(a, b));
    return *reinterpret_cast<unsigned*>(&h);
}

// async global->LDS DMA, 16B/lane; LDS dest = wave-uniform base + lane*16
__device__ __forceinline__ void async16(const ushort* g, ushort* l) {
    __builtin_amdgcn_global_load_lds(
        (const __attribute__((address_space(1))) unsigned int*)g,
        (__attribute__((address_space(3))) unsigned int*)l, 16, 0, 0);
}

// ---------------------------------------------------------------------------
// prep: blocks [0,8192) = x fp32->bf16 ; blocks [8192,8448) = weight
// transpose+convert. WT[(which*8+h)*64+n][d], WoT[n][d].
// ---------------------------------------------------------------------------
__global__ __launch_bounds__(256) void prep(const float* __restrict__ x,
                                            const float* __restrict__ Wq,
                                            const float* __restrict__ Wk,
                                            const float* __restrict__ Wv,
                                            const float* __restrict__ Wo,
                                            ushort* __restrict__ xb,
                                            ushort* __restrict__ WT,
                                            ushort* __restrict__ WoT) {
    __shared__ ushort T[64 * 72];
    const int tid = threadIdx.x;
    if (blockIdx.x < 8192) {
        const int idx = blockIdx.x * 256 + tid;
        const float4 v = reinterpret_cast<const float4*>(x)[idx];
        ushort4 o;
        o.x = f2bf(v.x); o.y = f2bf(v.y); o.z = f2bf(v.z); o.w = f2bf(v.w);
        reinterpret_cast<ushort4*>(xb)[idx] = o;
        return;
    }
    const int bid = blockIdx.x - 8192;
    const float* src; ushort* dst; int d0, n0, stride;
    if (bid < 192) {
        const int which = bid >> 6, h = (bid >> 3) & 7, rt = bid & 7;
        const float* Ws = (which == 0) ? Wq : (which == 1) ? Wk : Wv;
        src = Ws + (size_t)h * ND * NDK;
        dst = WT + (size_t)(which * NH + h) * NDK * ND;
        d0 = rt * 64; n0 = 0; stride = NDK;
    } else {
        const int t = bid - 192, rt = t >> 3, ct = t & 7;
        src = Wo; dst = WoT;
        d0 = rt * 64; n0 = ct * 64; stride = ND;
    }
    #pragma unroll
    for (int i = 0; i < 4; i++) {
        const int u = i * 256 + tid;
        const int row = u >> 4, cq = u & 15;
        const float4 v = *reinterpret_cast<const float4*>(&src[(size_t)(d0 + row) * stride + n0 + cq * 4]);
        T[(cq * 4 + 0) * 72 + row] = f2bf(v.x);
        T[(cq * 4 + 1) * 72 + row] = f2bf(v.y);
        T[(cq * 4 + 2) * 72 + row] = f2bf(v.z);
        T[(cq * 4 + 3) * 72 + row] = f2bf(v.w);
    }
    __syncthreads();
    #pragma unroll
    for (int i = 0; i < 2; i++) {
        const int u = i * 256 + tid;
        const int n = u >> 3, dq = u & 7;
        *reinterpret_cast<float4*>(&dst[(size_t)(n0 + n) * ND + d0 + dq * 8]) =
            *reinterpret_cast<float4*>(&T[n * 72 + dq * 8]);
    }
}

// ---------------------------------------------------------------------------
// proj: blocks [0,1024) = Q|K GEMM (128x128 tiles on [16384x1024]);
//       blocks [1024,1536) = V^T GEMM (per (b,h): VT[dk][s], 64x256 tiles).
// Union LDS (40 KB). B-slots permuted -> packed 8B bf16 stores.
// ---------------------------------------------------------------------------
__global__ __launch_bounds__(256) void proj(const ushort* __restrict__ xb,
                                            const ushort* __restrict__ WT,
                                            const float* __restrict__ bias,
                                            ushort* __restrict__ QKb,
                                            ushort* __restrict__ VT) {
    __shared__ ushort sm[20480];   // 40 KB
    const int tid = threadIdx.x;
    const int w = tid >> 6, lane = tid & 63, quad = lane >> 4, l16 = lane & 15;
    const int lr = lane >> 3, lc = lane & 7, cs = lc ^ lr, swz = l16 & 7;
    const float bb = bias[0];

    f32x4 acc[4][4];
    #pragma unroll
    for (int i = 0; i < 4; i++)
        #pragma unroll
        for (int j = 0; j < 4; j++) acc[i][j] = (f32x4){0.f, 0.f, 0.f, 0.f};

    if (blockIdx.x < 1024) {
        ushort* As = sm;            // 128x64
        ushort* Bs = sm + 8192;     // 128x64
        const int bid = blockIdx.x;
        const int m0 = (bid & 127) * 128, n0 = (bid >> 7) * 128;
        const int rw = (w & 1) * 64, cw = (w >> 1) * 64;
        for (int d0 = 0; d0 < ND; d0 += 64) {
            __syncthreads();
            #pragma unroll
            for (int t = 0; t < 4; t++) {
                const int rb = (w * 4 + t) * 8;
                async16(&xb[(size_t)(m0 + rb + lr) * ND + d0 + cs * 8], &As[rb * 64]);
                const int slot = rb + lr, nn = slot & 63;
                const int j = n0 + (slot & 64) + 4 * (nn & 15) + (nn >> 4);
                async16(&WT[(size_t)j * ND + d0 + cs * 8], &Bs[rb * 64]);
            }
            __syncthreads();
            #pragma unroll
            for (int ks = 0; ks < 2; ks++) {
                const int ch = ((ks * 4 + quad) ^ swz) * 8;
                bfrag a[4], bo[4];
                #pragma unroll
                for (int rf = 0; rf < 4; rf++) a[rf] = *(const bfrag*)&As[(rw + rf * 16 + l16) * 64 + ch];
                #pragma unroll
                for (int cf = 0; cf < 4; cf++) bo[cf] = *(const bfrag*)&Bs[(cw + cf * 16 + l16) * 64 + ch];
                #pragma unroll
                for (int rf = 0; rf < 4; rf++)
                    #pragma unroll
                    for (int cf = 0; cf < 4; cf++)
                        acc[rf][cf] = __builtin_amdgcn_mfma_f32_16x16x32_bf16(a[rf], bo[cf], acc[rf][cf], 0, 0, 0);
            }
        }
        #pragma unroll
        for (int rf = 0; rf < 4; rf++)
            #pragma unroll
            for (int r = 0; r < 4; r++) {
                const int row = m0 + rw + rf * 16 + quad * 4 + r;
                uint2 u;
                u.x = pk2bf(acc[rf][0][r] + bb, acc[rf][1][r] + bb);
                u.y = pk2bf(acc[rf][2][r] + bb, acc[rf][3][r] + bb);
                *(uint2*)&QKb[(size_t)row * 1024 + n0 + cw + 4 * l16] = u;
            }
    } else {
        ushort* As = sm;            // 64x64
        ushort* Bs = sm + 4096;     // 256x64
        const int bid = blockIdx.x - 1024;
        const int bh = bid >> 1, s0 = (bid & 1) * 256;
        const int b = bh >> 3, h = bh & 7;
        const int cw = w * 64;
        const ushort* Av = WT + (size_t)(2 * NH + h) * NDK * ND;
        const ushort* xrow = xb + (size_t)b * NS * ND;
        for (int d0 = 0; d0 < ND; d0 += 64) {
            __syncthreads();
            #pragma unroll
            for (int t = 0; t < 2; t++) {
                const int rb = w * 16 + t * 8;
                async16(&Av[(size_t)(rb + lr) * ND + d0 + cs * 8], &As[rb * 64]);
            }
            #pragma unroll
            for (int t = 0; t < 8; t++) {
                const int rb = (w * 8 + t) * 8;
                const int slot = rb + lr, nn = slot & 63;
                const int js = s0 + (slot & 192) + 4 * (nn & 15) + (nn >> 4);
                async16(&xrow[(size_t)js * ND + d0 + cs * 8], &Bs[rb * 64]);
            }
            __syncthreads();
            #pragma unroll
            for (int ks = 0; ks < 2; ks++) {
                const int ch = ((ks * 4 + quad) ^ swz) * 8;
                bfrag a[4], bo[4];
                #pragma unroll
                for (int rf = 0; rf < 4; rf++) a[rf] = *(const bfrag*)&As[(rf * 16 + l16) * 64 + ch];
                #pragma unroll
                for (int cf = 0; cf < 4; cf++) bo[cf] = *(const bfrag*)&Bs[(cw + cf * 16 + l16) * 64 + ch];
                #pragma unroll
                for (int rf = 0; rf < 4; rf++)
                    #pragma unroll
                    for (int cf = 0; cf < 4; cf++)
                        acc[rf][cf] = __builtin_amdgcn_mfma_f32_16x16x32_bf16(a[rf], bo[cf], acc[rf][cf], 0, 0, 0);
            }
        }
        ushort* vbase = VT + (size_t)bh * NDK * NS;
        #pragma unroll
        for (int rf = 0; rf < 4; rf++)
            #pragma unroll
            for (int r = 0; r < 4; r++) {
                const int dk = rf * 16 + quad * 4 + r;
                uint2 u;
                u.x = pk2bf(acc[rf][0][r] + bb, acc[rf][1][r] + bb);
                u.y = pk2bf(acc[rf][2][r] + bb, acc[rf][3][r] + bb);
                *(uint2*)&vbase[(size_t)dk * NS + s0 + cw + 4 * l16] = u;
            }
    }
}

// ---------------------------------------------------------------------------
// Flash attention, 128-row Q tile, DOUBLE-BUFFERED K/V DMA. 1024 blocks x 256.
// Loop shape: { issue DMA(kt+1) -> buf[nxt]; compute(kt) from buf[cur];
// barrier }. The barrier's vmcnt(0) drain lands after a full iteration of
// compute overlapped the DMA -> ~zero stall (vs full-latency stall before).
// One barrier/iter. buf[nxt] overwrite is safe: last read in iter kt-1,
// protected by the end-of-(kt-1) barrier. Q frags in registers; Ps overlays
// the Q staging buffer. Fixed-max softmax; row sums via ones-MFMA.
// ---------------------------------------------------------------------------
__global__ __launch_bounds__(256) void attn_mfma(const ushort* __restrict__ QKb,
                                                 const ushort* __restrict__ VT,
                                                 const int* __restrict__ mask,
                                                 ushort* __restrict__ Hb) {
    __shared__ ushort QP[128 * 72];    // Q staged at stride 64; then Ps stride 72
    __shared__ ushort Ks[2][64 * 64];
    __shared__ ushort Vs[2][64 * 64];
    const int id = blockIdx.x;
    const int bh = id & 255, b = bh >> 3, h = bh & 7;
    const int s0 = (id >> 8) * 128;
    const int tid = threadIdx.x;
    const int w = tid >> 6, lane = tid & 63, quad = lane >> 4, l16 = lane & 15;
    const int lr = lane >> 3, lc = lane & 7, cs = lc ^ lr, swz = l16 & 7;

    const ushort* qbase = QKb + (size_t)(b * NS + s0) * 1024 + h * 64;
    const ushort* kbase = QKb + (size_t)(b * NS) * 1024 + 512 + h * 64;
    const ushort* vbase = VT + (size_t)(b * NH + h) * NDK * NS;

    // rows this wave stages for K/V (slot-permuted), hoisted out of the loop
    const int rbA = (w * 2 + 0) * 8, nA = rbA + lr, jkA = 4 * (nA & 15) + (nA >> 4);
    const int rbB = (w * 2 + 1) * 8, nB = rbB + lr, jkB = 4 * (nB & 15) + (nB >> 4);

    // prologue: Q DMA + kt=0 K/V DMA, one drain
    #pragma unroll
    for (int t = 0; t < 4; t++) {
        const int rb = (w * 4 + t) * 8;
        async16(&qbase[(size_t)(rb + lr) * 1024 + cs * 8], &QP[rb * 64]);
    }
    async16(&kbase[(size_t)jkA * 1024 + cs * 8], &Ks[0][rbA * 64]);
    async16(&kbase[(size_t)jkB * 1024 + cs * 8], &Ks[0][rbB * 64]);
    async16(&vbase[(size_t)jkA * NS + cs * 8], &Vs[0][rbA * 64]);
    async16(&vbase[(size_t)jkB * NS + cs * 8], &Vs[0][rbB * 64]);
    __syncthreads();   // drains all DMA

    // Q fragments -> registers (wave rows w*32 .. w*32+31)
    bfrag qf[2][2];
    #pragma unroll
    for (int ks = 0; ks < 2; ks++)
        #pragma unroll
        for (int rf = 0; rf < 2; rf++)
            qf[ks][rf] = *(const bfrag*)&QP[(w * 32 + rf * 16 + l16) * 64 + ((ks * 4 + quad) ^ swz) * 8];
    // all waves' Q reads must complete before anyone writes Ps into this space
    asm volatile("s_waitcnt lgkmcnt(0)" ::: "memory");
    __syncthreads();
    ushort* Ps = QP;   // stride 72 from here on

    bfrag ones;
    #pragma unroll
    for (int i = 0; i < 8; i++) ones[i] = (short)0x3F80;   // bf16 1.0

    f32x4 acc_l[2];
    f32x4 acc_o[2][4];
    #pragma unroll
    for (int rf = 0; rf < 2; rf++) {
        acc_l[rf] = (f32x4){0.f, 0.f, 0.f, 0.f};
        #pragma unroll
        for (int c = 0; c < 4; c++) acc_o[rf][c] = (f32x4){0.f, 0.f, 0.f, 0.f};
    }

    #pragma unroll 2
    for (int kt = 0; kt < 8; kt++) {
        const int cur = kt & 1;
        // prefetch kt+1 into the other buffer (read last in iter kt-1;
        // end-of-(kt-1) barrier makes the overwrite safe)
        if (kt < 7) {
            const int nxt = cur ^ 1;
            const ushort* kb2 = kbase + (size_t)(kt + 1) * 64 * 1024;
            const ushort* vb2 = vbase + (size_t)(kt + 1) * 64;
            async16(&kb2[(size_t)jkA * 1024 + cs * 8], &Ks[nxt][rbA * 64]);
            async16(&kb2[(size_t)jkB * 1024 + cs * 8], &Ks[nxt][rbB * 64]);
            async16(&vb2[(size_t)jkA * NS + cs * 8], &Vs[nxt][rbA * 64]);
            async16(&vb2[(size_t)jkB * NS + cs * 8], &Vs[nxt][rbB * 64]);
        }

        // scores: rows w*32+rf*16+quad*4+r, cols = key 4*l16+c
        f32x4 sc[2][4];
        #pragma unroll
        for (int rf = 0; rf < 2; rf++)
            #pragma unroll
            for (int c = 0; c < 4; c++) sc[rf][c] = (f32x4){0.f, 0.f, 0.f, 0.f};
        #pragma unroll
        for (int ks = 0; ks < 2; ks++) {
            const int ch = ((ks * 4 + quad) ^ swz) * 8;
            bfrag bo[4];
            #pragma unroll
            for (int c = 0; c < 4; c++) bo[c] = *(const bfrag*)&Ks[cur][(c * 16 + l16) * 64 + ch];
            #pragma unroll
            for (int rf = 0; rf < 2; rf++)
                #pragma unroll
                for (int c = 0; c < 4; c++)
                    sc[rf][c] = __builtin_amdgcn_mfma_f32_16x16x32_bf16(qf[ks][rf], bo[c], sc[rf][c], 0, 0, 0);
        }

        // mask folded into fma bias: masked -> -inf -> exp2 = 0
        const int4 mk4 = *(const int4*)&mask[b * NS + kt * 64 + 4 * l16];
        float mb[4];
        mb[0] = mk4.x ? 0.f : -INFINITY;
        mb[1] = mk4.y ? 0.f : -INFINITY;
        mb[2] = mk4.z ? 0.f : -INFINITY;
        mb[3] = mk4.w ? 0.f : -INFINITY;
        #pragma unroll
        for (int rf = 0; rf < 2; rf++) {
            #pragma unroll
            for (int c = 0; c < 4; c++)
                #pragma unroll
                for (int r = 0; r < 4; r++)
                    sc[rf][c][r] = exp2f(fmaf(sc[rf][c][r], SCL, mb[c]));
            #pragma unroll
            for (int r = 0; r < 4; r++) {
                uint2 u;
                u.x = pk2bf(sc[rf][0][r], sc[rf][1][r]);
                u.y = pk2bf(sc[rf][2][r], sc[rf][3][r]);
                *(uint2*)&Ps[(w * 32 + rf * 16 + quad * 4 + r) * 72 + l16 * 4] = u;
            }
        }

        // O += P.V ; rowsum += P.1   (Ps rows wave-private)
        #pragma unroll
        for (int ks = 0; ks < 2; ks++) {
            const int ch = ((ks * 4 + quad) ^ swz) * 8;
            bfrag bo[4];
            #pragma unroll
            for (int c = 0; c < 4; c++) bo[c] = *(const bfrag*)&Vs[cur][(c * 16 + l16) * 64 + ch];
            #pragma unroll
            for (int rf = 0; rf < 2; rf++) {
                const bfrag a = *(const bfrag*)&Ps[(w * 32 + rf * 16 + l16) * 72 + ks * 32 + quad * 8];
                acc_l[rf] = __builtin_amdgcn_mfma_f32_16x16x32_bf16(a, ones, acc_l[rf], 0, 0, 0);
                #pragma unroll
                for (int c = 0; c < 4; c++)
                    acc_o[rf][c] = __builtin_amdgcn_mfma_f32_16x16x32_bf16(a, bo[c], acc_o[rf][c], 0, 0, 0);
            }
        }

        // end-of-iter barrier: vmcnt(0) drain of the kt+1 prefetch (had a
        // full compute phase in flight) + frees buf[cur] for iter kt+2
        if (kt < 7) __syncthreads();
    }

    // Hb[b, s, h*64+dk]; acc_o[rf][c][r] = O[row][dk=4*l16+c]
    ushort* hbase = Hb + (size_t)(b * NS + s0) * ND + h * 64;
    #pragma unroll
    for (int rf = 0; rf < 2; rf++)
        #pragma unroll
        for (int r = 0; r < 4; r++) {
            const float inv = 1.0f / acc_l[rf][r];
            const int row = w * 32 + rf * 16 + quad * 4 + r;
            uint2 u;
            u.x = pk2bf(acc_o[rf][0][r] * inv, acc_o[rf][1][r] * inv);
            u.y = pk2bf(acc_o[rf][2][r] * inv, acc_o[rf][3][r] * inv);
            *(uint2*)&hbase[(size_t)row * ND + 4 * l16] = u;
        }
}

// ---------------------------------------------------------------------------
// Output projection GEMM: out[16384][512] = Hb @ WoT^T + bias.
// 128x128 tiles, 512 blocks x 256. Permuted cols -> float4 stores.
// ---------------------------------------------------------------------------
__global__ __launch_bounds__(256) void out_gemm(const ushort* __restrict__ Hb,
                                                const ushort* __restrict__ WoT,
                                                const float* __restrict__ bias,
                                                float* __restrict__ out) {
    __shared__ ushort As[128 * 64];
    __shared__ ushort Bs[128 * 64];
    const int bid = blockIdx.x;
    const int m0 = (bid & 127) * 128, n0 = (bid >> 7) * 128;
    const int tid = threadIdx.x;
    const int w = tid >> 6, lane = tid & 63, quad = lane >> 4, l16 = lane & 15;
    const int lr = lane >> 3, lc = lane & 7, cs = lc ^ lr, swz = l16 & 7;
    const int rw = (w & 1) * 64, cw = (w >> 1) * 64;

    f32x4 acc[4][4];
    #pragma unroll
    for (int i = 0; i < 4; i++)
        #pragma unroll
        for (int j = 0; j < 4; j++) acc[i][j] = (f32x4){0.f, 0.f, 0.f, 0.f};

    for (int d0 = 0; d0 < ND; d0 += 64) {
        __syncthreads();
        #pragma unroll
        for (int t = 0; t < 4; t++) {
            const int rb = (w * 4 + t) * 8;
            async16(&Hb[(size_t)(m0 + rb + lr) * ND + d0 + cs * 8], &As[rb * 64]);
            const int slot = rb + lr, nn = slot & 63;
            const int j = n0 + (slot & 64) + 4 * (nn & 15) + (nn >> 4);
            async16(&WoT[(size_t)j * ND + d0 + cs * 8], &Bs[rb * 64]);
        }
        __syncthreads();
        #pragma unroll
        for (int ks = 0; ks < 2; ks++) {
            const int ch = ((ks * 4 + quad) ^ swz) * 8;
            bfrag a[4], bo[4];
            #pragma unroll
            for (int rf = 0; rf < 4; rf++) a[rf] = *(const bfrag*)&As[(rw + rf * 16 + l16) * 64 + ch];
            #pragma unroll
            for (int cf = 0; cf < 4; cf++) bo[cf] = *(const bfrag*)&Bs[(cw + cf * 16 + l16) * 64 + ch];
            #pragma unroll
            for (int rf = 0; rf < 4; rf++)
                #pragma unroll
                for (int cf = 0; cf < 4; cf++)
                    acc[rf][cf] = __builtin_amdgcn_mfma_f32_16x16x32_bf16(a[rf], bo[cf], acc[rf][cf], 0, 0, 0);
        }
    }

    const float bb = bias[0];
    #pragma unroll
    for (int rf = 0; rf < 4; rf++)
        #pragma unroll
        for (int r = 0; r < 4; r++) {
            const int row = m0 + rw + rf * 16 + quad * 4 + r;
            float4 v;
            v.x = acc[rf][0][r] + bb; v.y = acc[rf][1][r] + bb;
            v.z = acc[rf][2][r] + bb; v.w = acc[rf][3][r] + bb;
            *(float4*)&out[(size_t)row * ND + n0 + cw + 4 * l16] = v;
        }
}

// ---------------------------------------------------------------------------
extern "C" void kernel_launch(void* const* d_in, const int* in_sizes, int n_in,
                              void* d_out, int out_size, void* d_ws, size_t ws_size,
                              hipStream_t stream) {
    const float* x    = (const float*)d_in[0];
    const int*   mask = (const int*)  d_in[1];
    const float* Wq   = (const float*)d_in[2];
    const float* Wk   = (const float*)d_in[3];
    const float* Wv   = (const float*)d_in[4];
    const float* Wo   = (const float*)d_in[5];
    const float* bias = (const float*)d_in[6];
    float* out = (float*)d_out;

    const size_t TE = (size_t)NB * NS * ND;   // 8,388,608
    ushort* xb  = (ushort*)d_ws;
    ushort* WT  = xb  + TE;                              // 1536*512
    ushort* WoT = WT  + (size_t)3 * NH * NDK * ND;       // 512*512
    ushort* QKb = WoT + (size_t)ND * ND;                 // 16384*1024
    ushort* VT  = QKb + (size_t)NB * NS * 2 * ND;        // 32*8*64*512
    ushort* Hb  = VT  + TE;                              // 16384*512

    prep<<<dim3(8448), dim3(256), 0, stream>>>(x, Wq, Wk, Wv, Wo, xb, WT, WoT);
    proj<<<dim3(1536), dim3(256), 0, stream>>>(xb, WT, bias, QKb, VT);
    attn_mfma<<<dim3(1024), dim3(256), 0, stream>>>(QKb, VT, mask, Hb);
    out_gemm<<<dim3(512), dim3(256), 0, stream>>>(Hb, WoT, bias, out);
}

// Round 8
// 179.646 us; speedup vs baseline: 1.0579x; 1.0015x over previous
//
#include <hip/hip_runtime.h>
#include <hip/hip_bf16.h>
#include <math.h>

#define NB 32
#define NS 512
#define ND 512
#define NH 8
#define NDK 64

typedef __attribute__((ext_vector_type(8))) short bfrag;   // 8 x bf16 (4 VGPRs)
typedef __attribute__((ext_vector_type(4))) float f32x4;   // MFMA C/D

// 0.125 * log2(e): folds 1/sqrt(dk) into the exp2 argument
#define SCL 0.18033688011112042592f

__device__ __forceinline__ ushort f2bf(float f) {
    union { float f; unsigned u; } v; v.f = f;
    unsigned u = v.u;
    return (ushort)((u + 0x7fffu + ((u >> 16) & 1u)) >> 16);   // RNE
}

__device__ __forceinline__ unsigned pk2bf(float a, float b) {
    __hip_bfloat162 h = __float22bfloat162_rn(make_float2(a, b));
    return *reinterpret_cast<unsigned*>(&h);
}

// async global->LDS DMA, 16B/lane; LDS dest = wave-uniform base + lane*16
__device__ __forceinline__ void async16(const ushort* g, ushort* l) {
    __builtin_amdgcn_global_load_lds(
        (const __attribute__((address_space(1))) unsigned int*)g,
        (__attribute__((address_space(3))) unsigned int*)l, 16, 0, 0);
}

// ---------------------------------------------------------------------------
// prep: blocks [0,8192) = x fp32->bf16 ; blocks [8192,8448) = weight
// transpose+convert. WT[(which*8+h)*64+n][d], WoT[n][d].
// ---------------------------------------------------------------------------
__global__ __launch_bounds__(256) void prep(const float* __restrict__ x,
                                            const float* __restrict__ Wq,
                                            const float* __restrict__ Wk,
                                            const float* __restrict__ Wv,
                                            const float* __restrict__ Wo,
                                            ushort* __restrict__ xb,
                                            ushort* __restrict__ WT,
                                            ushort* __restrict__ WoT) {
    __shared__ ushort T[64 * 72];
    const int tid = threadIdx.x;
    if (blockIdx.x < 8192) {
        const int idx = blockIdx.x * 256 + tid;
        const float4 v = reinterpret_cast<const float4*>(x)[idx];
        ushort4 o;
        o.x = f2bf(v.x); o.y = f2bf(v.y); o.z = f2bf(v.z); o.w = f2bf(v.w);
        reinterpret_cast<ushort4*>(xb)[idx] = o;
        return;
    }
    const int bid = blockIdx.x - 8192;
    const float* src; ushort* dst; int d0, n0, stride;
    if (bid < 192) {
        const int which = bid >> 6, h = (bid >> 3) & 7, rt = bid & 7;
        const float* Ws = (which == 0) ? Wq : (which == 1) ? Wk : Wv;
        src = Ws + (size_t)h * ND * NDK;
        dst = WT + (size_t)(which * NH + h) * NDK * ND;
        d0 = rt * 64; n0 = 0; stride = NDK;
    } else {
        const int t = bid - 192, rt = t >> 3, ct = t & 7;
        src = Wo; dst = WoT;
        d0 = rt * 64; n0 = ct * 64; stride = ND;
    }
    #pragma unroll
    for (int i = 0; i < 4; i++) {
        const int u = i * 256 + tid;
        const int row = u >> 4, cq = u & 15;
        const float4 v = *reinterpret_cast<const float4*>(&src[(size_t)(d0 + row) * stride + n0 + cq * 4]);
        T[(cq * 4 + 0) * 72 + row] = f2bf(v.x);
        T[(cq * 4 + 1) * 72 + row] = f2bf(v.y);
        T[(cq * 4 + 2) * 72 + row] = f2bf(v.z);
        T[(cq * 4 + 3) * 72 + row] = f2bf(v.w);
    }
    __syncthreads();
    #pragma unroll
    for (int i = 0; i < 2; i++) {
        const int u = i * 256 + tid;
        const int n = u >> 3, dq = u & 7;
        *reinterpret_cast<float4*>(&dst[(size_t)(n0 + n) * ND + d0 + dq * 8]) =
            *reinterpret_cast<float4*>(&T[n * 72 + dq * 8]);
    }
}

// ---------------------------------------------------------------------------
// proj: blocks [0,1024) = Q|K GEMM (128x128 tiles on [16384x1024]);
//       blocks [1024,1536) = V^T GEMM (per (b,h): VT[dk][s], 64x256 tiles).
// Union LDS (40 KB). B-slots permuted -> packed 8B bf16 stores.
// ---------------------------------------------------------------------------
__global__ __launch_bounds__(256) void proj(const ushort* __restrict__ xb,
                                            const ushort* __restrict__ WT,
                                            const float* __restrict__ bias,
                                            ushort* __restrict__ QKb,
                                            ushort* __restrict__ VT) {
    __shared__ ushort sm[20480];   // 40 KB
    const int tid = threadIdx.x;
    const int w = tid >> 6, lane = tid & 63, quad = lane >> 4, l16 = lane & 15;
    const int lr = lane >> 3, lc = lane & 7, cs = lc ^ lr, swz = l16 & 7;
    const float bb = bias[0];

    f32x4 acc[4][4];
    #pragma unroll
    for (int i = 0; i < 4; i++)
        #pragma unroll
        for (int j = 0; j < 4; j++) acc[i][j] = (f32x4){0.f, 0.f, 0.f, 0.f};

    if (blockIdx.x < 1024) {
        ushort* As = sm;            // 128x64
        ushort* Bs = sm + 8192;     // 128x64
        const int bid = blockIdx.x;
        const int m0 = (bid & 127) * 128, n0 = (bid >> 7) * 128;
        const int rw = (w & 1) * 64, cw = (w >> 1) * 64;
        for (int d0 = 0; d0 < ND; d0 += 64) {
            __syncthreads();
            #pragma unroll
            for (int t = 0; t < 4; t++) {
                const int rb = (w * 4 + t) * 8;
                async16(&xb[(size_t)(m0 + rb + lr) * ND + d0 + cs * 8], &As[rb * 64]);
                const int slot = rb + lr, nn = slot & 63;
                const int j = n0 + (slot & 64) + 4 * (nn & 15) + (nn >> 4);
                async16(&WT[(size_t)j * ND + d0 + cs * 8], &Bs[rb * 64]);
            }
            __syncthreads();
            #pragma unroll
            for (int ks = 0; ks < 2; ks++) {
                const int ch = ((ks * 4 + quad) ^ swz) * 8;
                bfrag a[4], bo[4];
                #pragma unroll
                for (int rf = 0; rf < 4; rf++) a[rf] = *(const bfrag*)&As[(rw + rf * 16 + l16) * 64 + ch];
                #pragma unroll
                for (int cf = 0; cf < 4; cf++) bo[cf] = *(const bfrag*)&Bs[(cw + cf * 16 + l16) * 64 + ch];
                #pragma unroll
                for (int rf = 0; rf < 4; rf++)
                    #pragma unroll
                    for (int cf = 0; cf < 4; cf++)
                        acc[rf][cf] = __builtin_amdgcn_mfma_f32_16x16x32_bf16(a[rf], bo[cf], acc[rf][cf], 0, 0, 0);
            }
        }
        #pragma unroll
        for (int rf = 0; rf < 4; rf++)
            #pragma unroll
            for (int r = 0; r < 4; r++) {
                const int row = m0 + rw + rf * 16 + quad * 4 + r;
                uint2 u;
                u.x = pk2bf(acc[rf][0][r] + bb, acc[rf][1][r] + bb);
                u.y = pk2bf(acc[rf][2][r] + bb, acc[rf][3][r] + bb);
                *(uint2*)&QKb[(size_t)row * 1024 + n0 + cw + 4 * l16] = u;
            }
    } else {
        ushort* As = sm;            // 64x64
        ushort* Bs = sm + 4096;     // 256x64
        const int bid = blockIdx.x - 1024;
        const int bh = bid >> 1, s0 = (bid & 1) * 256;
        const int b = bh >> 3, h = bh & 7;
        const int cw = w * 64;
        const ushort* Av = WT + (size_t)(2 * NH + h) * NDK * ND;
        const ushort* xrow = xb + (size_t)b * NS * ND;
        for (int d0 = 0; d0 < ND; d0 += 64) {
            __syncthreads();
            #pragma unroll
            for (int t = 0; t < 2; t++) {
                const int rb = w * 16 + t * 8;
                async16(&Av[(size_t)(rb + lr) * ND + d0 + cs * 8], &As[rb * 64]);
            }
            #pragma unroll
            for (int t = 0; t < 8; t++) {
                const int rb = (w * 8 + t) * 8;
                const int slot = rb + lr, nn = slot & 63;
                const int js = s0 + (slot & 192) + 4 * (nn & 15) + (nn >> 4);
                async16(&xrow[(size_t)js * ND + d0 + cs * 8], &Bs[rb * 64]);
            }
            __syncthreads();
            #pragma unroll
            for (int ks = 0; ks < 2; ks++) {
                const int ch = ((ks * 4 + quad) ^ swz) * 8;
                bfrag a[4], bo[4];
                #pragma unroll
                for (int rf = 0; rf < 4; rf++) a[rf] = *(const bfrag*)&As[(rf * 16 + l16) * 64 + ch];
                #pragma unroll
                for (int cf = 0; cf < 4; cf++) bo[cf] = *(const bfrag*)&Bs[(cw + cf * 16 + l16) * 64 + ch];
                #pragma unroll
                for (int rf = 0; rf < 4; rf++)
                    #pragma unroll
                    for (int cf = 0; cf < 4; cf++)
                        acc[rf][cf] = __builtin_amdgcn_mfma_f32_16x16x32_bf16(a[rf], bo[cf], acc[rf][cf], 0, 0, 0);
            }
        }
        ushort* vbase = VT + (size_t)bh * NDK * NS;
        #pragma unroll
        for (int rf = 0; rf < 4; rf++)
            #pragma unroll
            for (int r = 0; r < 4; r++) {
                const int dk = rf * 16 + quad * 4 + r;
                uint2 u;
                u.x = pk2bf(acc[rf][0][r] + bb, acc[rf][1][r] + bb);
                u.y = pk2bf(acc[rf][2][r] + bb, acc[rf][3][r] + bb);
                *(uint2*)&vbase[(size_t)dk * NS + s0 + cw + 4 * l16] = u;
            }
    }
}

// ---------------------------------------------------------------------------
// Flash attention, 128-row Q tile, double-buffered K/V DMA. 1024 blocks x 256.
// Softmax exp via raw v_exp_f32 (__builtin_amdgcn_exp2f): libm exp2f was
// ~500 VALU inst/iter (no -ffast-math) — the dominant VALU term. HW exp2
// gives 2^-inf = 0, preserving exact masked-key semantics.
// ---------------------------------------------------------------------------
__global__ __launch_bounds__(256) void attn_mfma(const ushort* __restrict__ QKb,
                                                 const ushort* __restrict__ VT,
                                                 const int* __restrict__ mask,
                                                 ushort* __restrict__ Hb) {
    __shared__ ushort QP[128 * 72];    // Q staged at stride 64; then Ps stride 72
    __shared__ ushort Ks[2][64 * 64];
    __shared__ ushort Vs[2][64 * 64];
    const int id = blockIdx.x;
    const int bh = id & 255, b = bh >> 3, h = bh & 7;
    const int s0 = (id >> 8) * 128;
    const int tid = threadIdx.x;
    const int w = tid >> 6, lane = tid & 63, quad = lane >> 4, l16 = lane & 15;
    const int lr = lane >> 3, lc = lane & 7, cs = lc ^ lr, swz = l16 & 7;

    const ushort* qbase = QKb + (size_t)(b * NS + s0) * 1024 + h * 64;
    const ushort* kbase = QKb + (size_t)(b * NS) * 1024 + 512 + h * 64;
    const ushort* vbase = VT + (size_t)(b * NH + h) * NDK * NS;

    // rows this wave stages for K/V (slot-permuted), hoisted out of the loop
    const int rbA = (w * 2 + 0) * 8, nA = rbA + lr, jkA = 4 * (nA & 15) + (nA >> 4);
    const int rbB = (w * 2 + 1) * 8, nB = rbB + lr, jkB = 4 * (nB & 15) + (nB >> 4);

    // prologue: Q DMA + kt=0 K/V DMA, one drain
    #pragma unroll
    for (int t = 0; t < 4; t++) {
        const int rb = (w * 4 + t) * 8;
        async16(&qbase[(size_t)(rb + lr) * 1024 + cs * 8], &QP[rb * 64]);
    }
    async16(&kbase[(size_t)jkA * 1024 + cs * 8], &Ks[0][rbA * 64]);
    async16(&kbase[(size_t)jkB * 1024 + cs * 8], &Ks[0][rbB * 64]);
    async16(&vbase[(size_t)jkA * NS + cs * 8], &Vs[0][rbA * 64]);
    async16(&vbase[(size_t)jkB * NS + cs * 8], &Vs[0][rbB * 64]);
    __syncthreads();   // drains all DMA

    // Q fragments -> registers (wave rows w*32 .. w*32+31)
    bfrag qf[2][2];
    #pragma unroll
    for (int ks = 0; ks < 2; ks++)
        #pragma unroll
        for (int rf = 0; rf < 2; rf++)
            qf[ks][rf] = *(const bfrag*)&QP[(w * 32 + rf * 16 + l16) * 64 + ((ks * 4 + quad) ^ swz) * 8];
    // all waves' Q reads must complete before anyone writes Ps into this space
    asm volatile("s_waitcnt lgkmcnt(0)" ::: "memory");
    __syncthreads();
    ushort* Ps = QP;   // stride 72 from here on

    bfrag ones;
    #pragma unroll
    for (int i = 0; i < 8; i++) ones[i] = (short)0x3F80;   // bf16 1.0

    f32x4 acc_l[2];
    f32x4 acc_o[2][4];
    #pragma unroll
    for (int rf = 0; rf < 2; rf++) {
        acc_l[rf] = (f32x4){0.f, 0.f, 0.f, 0.f};
        #pragma unroll
        for (int c = 0; c < 4; c++) acc_o[rf][c] = (f32x4){0.f, 0.f, 0.f, 0.f};
    }

    #pragma unroll 2
    for (int kt = 0; kt < 8; kt++) {
        const int cur = kt & 1;
        // prefetch kt+1 into the other buffer (read last in iter kt-1;
        // end-of-(kt-1) barrier makes the overwrite safe)
        if (kt < 7) {
            const int nxt = cur ^ 1;
            const ushort* kb2 = kbase + (size_t)(kt + 1) * 64 * 1024;
            const ushort* vb2 = vbase + (size_t)(kt + 1) * 64;
            async16(&kb2[(size_t)jkA * 1024 + cs * 8], &Ks[nxt][rbA * 64]);
            async16(&kb2[(size_t)jkB * 1024 + cs * 8], &Ks[nxt][rbB * 64]);
            async16(&vb2[(size_t)jkA * NS + cs * 8], &Vs[nxt][rbA * 64]);
            async16(&vb2[(size_t)jkB * NS + cs * 8], &Vs[nxt][rbB * 64]);
        }

        // scores: rows w*32+rf*16+quad*4+r, cols = key 4*l16+c
        f32x4 sc[2][4];
        #pragma unroll
        for (int rf = 0; rf < 2; rf++)
            #pragma unroll
            for (int c = 0; c < 4; c++) sc[rf][c] = (f32x4){0.f, 0.f, 0.f, 0.f};
        #pragma unroll
        for (int ks = 0; ks < 2; ks++) {
            const int ch = ((ks * 4 + quad) ^ swz) * 8;
            bfrag bo[4];
            #pragma unroll
            for (int c = 0; c < 4; c++) bo[c] = *(const bfrag*)&Ks[cur][(c * 16 + l16) * 64 + ch];
            #pragma unroll
            for (int rf = 0; rf < 2; rf++)
                #pragma unroll
                for (int c = 0; c < 4; c++)
                    sc[rf][c] = __builtin_amdgcn_mfma_f32_16x16x32_bf16(qf[ks][rf], bo[c], sc[rf][c], 0, 0, 0);
        }

        // mask folded into fma bias: masked -> -inf -> v_exp_f32 = 0
        const int4 mk4 = *(const int4*)&mask[b * NS + kt * 64 + 4 * l16];
        float mb[4];
        mb[0] = mk4.x ? 0.f : -INFINITY;
        mb[1] = mk4.y ? 0.f : -INFINITY;
        mb[2] = mk4.z ? 0.f : -INFINITY;
        mb[3] = mk4.w ? 0.f : -INFINITY;
        #pragma unroll
        for (int rf = 0; rf < 2; rf++) {
            #pragma unroll
            for (int c = 0; c < 4; c++)
                #pragma unroll
                for (int r = 0; r < 4; r++)
                    sc[rf][c][r] = __builtin_amdgcn_exp2f(fmaf(sc[rf][c][r], SCL, mb[c]));
            #pragma unroll
            for (int r = 0; r < 4; r++) {
                uint2 u;
                u.x = pk2bf(sc[rf][0][r], sc[rf][1][r]);
                u.y = pk2bf(sc[rf][2][r], sc[rf][3][r]);
                *(uint2*)&Ps[(w * 32 + rf * 16 + quad * 4 + r) * 72 + l16 * 4] = u;
            }
        }

        // O += P.V ; rowsum += P.1   (Ps rows wave-private)
        #pragma unroll
        for (int ks = 0; ks < 2; ks++) {
            const int ch = ((ks * 4 + quad) ^ swz) * 8;
            bfrag bo[4];
            #pragma unroll
            for (int c = 0; c < 4; c++) bo[c] = *(const bfrag*)&Vs[cur][(c * 16 + l16) * 64 + ch];
            #pragma unroll
            for (int rf = 0; rf < 2; rf++) {
                const bfrag a = *(const bfrag*)&Ps[(w * 32 + rf * 16 + l16) * 72 + ks * 32 + quad * 8];
                acc_l[rf] = __builtin_amdgcn_mfma_f32_16x16x32_bf16(a, ones, acc_l[rf], 0, 0, 0);
                #pragma unroll
                for (int c = 0; c < 4; c++)
                    acc_o[rf][c] = __builtin_amdgcn_mfma_f32_16x16x32_bf16(a, bo[c], acc_o[rf][c], 0, 0, 0);
            }
        }

        // end-of-iter barrier: vmcnt(0) drain of the kt+1 prefetch (had a
        // full compute phase in flight) + frees buf[cur] for iter kt+2
        if (kt < 7) __syncthreads();
    }

    // Hb[b, s, h*64+dk]; acc_o[rf][c][r] = O[row][dk=4*l16+c]
    ushort* hbase = Hb + (size_t)(b * NS + s0) * ND + h * 64;
    #pragma unroll
    for (int rf = 0; rf < 2; rf++)
        #pragma unroll
        for (int r = 0; r < 4; r++) {
            const float inv = 1.0f / acc_l[rf][r];
            const int row = w * 32 + rf * 16 + quad * 4 + r;
            uint2 u;
            u.x = pk2bf(acc_o[rf][0][r] * inv, acc_o[rf][1][r] * inv);
            u.y = pk2bf(acc_o[rf][2][r] * inv, acc_o[rf][3][r] * inv);
            *(uint2*)&hbase[(size_t)row * ND + 4 * l16] = u;
        }
}

// ---------------------------------------------------------------------------
// Output projection GEMM: out[16384][512] = Hb @ WoT^T + bias.
// 128x128 tiles, 512 blocks x 256. Permuted cols -> float4 stores.
// ---------------------------------------------------------------------------
__global__ __launch_bounds__(256) void out_gemm(const ushort* __restrict__ Hb,
                                                const ushort* __restrict__ WoT,
                                                const float* __restrict__ bias,
                                                float* __restrict__ out) {
    __shared__ ushort As[128 * 64];
    __shared__ ushort Bs[128 * 64];
    const int bid = blockIdx.x;
    const int m0 = (bid & 127) * 128, n0 = (bid >> 7) * 128;
    const int tid = threadIdx.x;
    const int w = tid >> 6, lane = tid & 63, quad = lane >> 4, l16 = lane & 15;
    const int lr = lane >> 3, lc = lane & 7, cs = lc ^ lr, swz = l16 & 7;
    const int rw = (w & 1) * 64, cw = (w >> 1) * 64;

    f32x4 acc[4][4];
    #pragma unroll
    for (int i = 0; i < 4; i++)
        #pragma unroll
        for (int j = 0; j < 4; j++) acc[i][j] = (f32x4){0.f, 0.f, 0.f, 0.f};

    for (int d0 = 0; d0 < ND; d0 += 64) {
        __syncthreads();
        #pragma unroll
        for (int t = 0; t < 4; t++) {
            const int rb = (w * 4 + t) * 8;
            async16(&Hb[(size_t)(m0 + rb + lr) * ND + d0 + cs * 8], &As[rb * 64]);
            const int slot = rb + lr, nn = slot & 63;
            const int j = n0 + (slot & 64) + 4 * (nn & 15) + (nn >> 4);
            async16(&WoT[(size_t)j * ND + d0 + cs * 8], &Bs[rb * 64]);
        }
        __syncthreads();
        #pragma unroll
        for (int ks = 0; ks < 2; ks++) {
            const int ch = ((ks * 4 + quad) ^ swz) * 8;
            bfrag a[4], bo[4];
            #pragma unroll
            for (int rf = 0; rf < 4; rf++) a[rf] = *(const bfrag*)&As[(rw + rf * 16 + l16) * 64 + ch];
            #pragma unroll
            for (int cf = 0; cf < 4; cf++) bo[cf] = *(const bfrag*)&Bs[(cw + cf * 16 + l16) * 64 + ch];
            #pragma unroll
            for (int rf = 0; rf < 4; rf++)
                #pragma unroll
                for (int cf = 0; cf < 4; cf++)
                    acc[rf][cf] = __builtin_amdgcn_mfma_f32_16x16x32_bf16(a[rf], bo[cf], acc[rf][cf], 0, 0, 0);
        }
    }

    const float bb = bias[0];
    #pragma unroll
    for (int rf = 0; rf < 4; rf++)
        #pragma unroll
        for (int r = 0; r < 4; r++) {
            const int row = m0 + rw + rf * 16 + quad * 4 + r;
            float4 v;
            v.x = acc[rf][0][r] + bb; v.y = acc[rf][1][r] + bb;
            v.z = acc[rf][2][r] + bb; v.w = acc[rf][3][r] + bb;
            *(float4*)&out[(size_t)row * ND + n0 + cw + 4 * l16] = v;
        }
}

// ---------------------------------------------------------------------------
extern "C" void kernel_launch(void* const* d_in, const int* in_sizes, int n_in,
                              void* d_out, int out_size, void* d_ws, size_t ws_size,
                              hipStream_t stream) {
    const float* x    = (const float*)d_in[0];
    const int*   mask = (const int*)  d_in[1];
    const float* Wq   = (const float*)d_in[2];
    const float* Wk   = (const float*)d_in[3];
    const float* Wv   = (const float*)d_in[4];
    const float* Wo   = (const float*)d_in[5];
    const float* bias = (const float*)d_in[6];
    float* out = (float*)d_out;

    const size_t TE = (size_t)NB * NS * ND;   // 8,388,608
    ushort* xb  = (ushort*)d_ws;
    ushort* WT  = xb  + TE;                              // 1536*512
    ushort* WoT = WT  + (size_t)3 * NH * NDK * ND;       // 512*512
    ushort* QKb = WoT + (size_t)ND * ND;                 // 16384*1024
    ushort* VT  = QKb + (size_t)NB * NS * 2 * ND;        // 32*8*64*512
    ushort* Hb  = VT  + TE;                              // 16384*512

    prep<<<dim3(8448), dim3(256), 0, stream>>>(x, Wq, Wk, Wv, Wo, xb, WT, WoT);
    proj<<<dim3(1536), dim3(256), 0, stream>>>(xb, WT, bias, QKb, VT);
    attn_mfma<<<dim3(1024), dim3(256), 0, stream>>>(QKb, VT, mask, Hb);
    out_gemm<<<dim3(512), dim3(256), 0, stream>>>(Hb, WoT, bias, out);
}